// Round 9
// baseline (369.656 us; speedup 1.0000x reference)
//
#include <hip/hip_runtime.h>
#include <hip/hip_bf16.h>
#include <stdint.h>

// out[b, n] = sum_k weight[b, perm(k)] * fc_w[n, k] + fc_b[n]
// Prep: convert fc_w fp32->bf16 (32 MB). GEMM: 256^2 8-phase schedule, A
// permute+convert fused as reg-staged LDS staging, XCD-grouped block map.
// ROUND-7 CHANGE (vmcnt FIFO fix): both ARL halves issued at P1; ONE counted
// wait per tile (vmcnt(2) at P3, after B0(T+2) issue) so no just-issued load
// is ever drained; both AWRs after the wait; P4 has no wait.
// ROUND-8/9: identical resubmits — rounds 7 and 8 died on infra
// (UnresponsiveContainer), produced no measurement.

using f32x4   = __attribute__((ext_vector_type(4))) float;
using bf16x8  = __attribute__((ext_vector_type(8))) __bf16;
using ushort8 = __attribute__((ext_vector_type(8))) unsigned short;

#define B_ROWS 8192
#define K_TOT  8192
#define N_OUT  2048
#define BK     64
#define NT     (K_TOT / BK)  // 128 K-tiles

__device__ __forceinline__ unsigned short f2bf(float f) {
  union { float f; unsigned int u; } v;
  v.f = f;
  unsigned int r = v.u + 0x7FFFu + ((v.u >> 16) & 1u);  // RNE
  return (unsigned short)(r >> 16);
}

__device__ __forceinline__ int perm_pack(int s1, int s2) {
  int mid = s1 ? 1 : 2;
  int r1 = s1 ? 2 : 1;
  int r2 = s2 ? 3 : mid;
  int r3 = s2 ? mid : 3;
  return (r1 << 2) | (r2 << 4) | (r3 << 6);  // r0=0 in bits 0-1
}

__device__ __forceinline__ int perm_src(int r, int s1, int s2) {
  int mid = s1 ? 1 : 2;
  return (r == 0) ? 0
       : (r == 1) ? (s1 ? 2 : 1)
       : (r == 2) ? (s2 ? 3 : mid)
                  : (s2 ? mid : 3);
}

// -------- prep: convert fc_w [2048][8192] fp32 -> bf16 --------
__global__ __launch_bounds__(256) void k_prep_w(
    const float* __restrict__ fw, unsigned short* __restrict__ wbf) {
  const size_t base = ((size_t)blockIdx.x * 256 + threadIdx.x) * 8;
  f32x4 v0 = *(const f32x4*)(fw + base);
  f32x4 v1 = *(const f32x4*)(fw + base + 4);
  ushort8 o;
#pragma unroll
  for (int j = 0; j < 4; ++j) o[j] = f2bf(v0[j]);
#pragma unroll
  for (int j = 0; j < 4; ++j) o[4 + j] = f2bf(v1[j]);
  *(ushort8*)(wbf + base) = o;
}

// -------- GEMM --------
__device__ __forceinline__ void gload16(const unsigned short* g,
                                        const unsigned short* l) {
  __builtin_amdgcn_global_load_lds(
      (__attribute__((address_space(1))) void*)(uintptr_t)(const void*)g,
      (__attribute__((address_space(3))) void*)(unsigned int)(uintptr_t)(const void*)l,
      16, 0, 0);
}

#define VM0 asm volatile("s_waitcnt vmcnt(0)" ::: "memory")
#define VM2 asm volatile("s_waitcnt vmcnt(2)" ::: "memory")
#define NOW ((void)0)
#define LGKM0_FENCE do { \
    asm volatile("s_waitcnt lgkmcnt(0)" ::: "memory"); \
    __builtin_amdgcn_sched_barrier(0); } while (0)

// LDS: per buf 64 KiB = A [256 rows][128 B] | B [256 rows][128 B]; 2 bufs.
#define LDA(BU, MH, M, KKI) \
  (*(const bf16x8*)(smb + (BU)*65536 + aBase + ((MH)*64 + (M)*16)*128 + colsw[KKI]))
#define LDB(BU, NH, N, KKI) \
  (*(const bf16x8*)(smb + (BU)*65536 + 32768 + bBase + ((NH)*32 + (N)*16)*128 + colsw[KKI]))

#define ALD(BUF, MH) do { \
  _Pragma("unroll") for (int m_ = 0; m_ < 4; ++m_) { \
    aR0[m_] = LDA(BUF, MH, m_, 0); aR1[m_] = LDA(BUF, MH, m_, 1); } \
} while (0)

// B half-tile (128 rows x 64 k) via 2 gload16, pre-swizzled source slot
#define STAGEB(BUF, H, T) do { \
  gload16(gB + (size_t)((H)*128 + row0) * K_TOT + (size_t)(T)*BK + sl0, \
          smu + (BUF)*32768 + 16384 + (H)*8192 + tid*8); \
  gload16(gB + (size_t)((H)*128 + row1) * K_TOT + (size_t)(T)*BK + sl0, \
          smu + (BUF)*32768 + 16384 + (H)*8192 + 4096 + tid*8); \
} while (0)

// A reg loads: 16 contiguous fp32 of thread's row, permuted block offset
#define AOFF(PK, TK) \
  ((size_t)((((PK) >> ((((TK) >> 5)) << 1)) & 3) << 11) + (size_t)(((TK) & 31) << 6))
#define ARL0(TK) do { const float* p_ = pA0 + AOFF(PA0, TK); \
  a0f[0] = *(const f32x4*)p_;        a0f[1] = *(const f32x4*)(p_ + 4); \
  a0f[2] = *(const f32x4*)(p_ + 8);  a0f[3] = *(const f32x4*)(p_ + 12); } while (0)
#define ARL1(TK) do { const float* p_ = pA1 + AOFF(PA1, TK); \
  a1f[0] = *(const f32x4*)p_;        a1f[1] = *(const f32x4*)(p_ + 4); \
  a1f[2] = *(const f32x4*)(p_ + 8);  a1f[3] = *(const f32x4*)(p_ + 12); } while (0)

// convert 16 fp32 -> bf16, swizzled ds_write into A region of BUF, half H
#define AWR(BUF, H, AF) do { \
  bf16x8 lo_, hi_; \
  _Pragma("unroll") for (int j_ = 0; j_ < 4; ++j_) { \
    lo_[j_]     = (__bf16)AF[0][j_]; lo_[4 + j_] = (__bf16)AF[1][j_]; \
    hi_[j_]     = (__bf16)AF[2][j_]; hi_[4 + j_] = (__bf16)AF[3][j_]; } \
  char* d_ = smw + (BUF)*65536 + ((H)*128 + arow) * 128; \
  *(bf16x8*)(d_ + wb0) = lo_; *(bf16x8*)(d_ + wb1) = hi_; \
} while (0)

#define QUAD(MH, NH, B0A, B1A) do { \
  _Pragma("unroll") for (int m_ = 0; m_ < 4; ++m_) \
    _Pragma("unroll") for (int n_ = 0; n_ < 2; ++n_) { \
      acc[(MH)*4+m_][(NH)*2+n_] = __builtin_amdgcn_mfma_f32_16x16x32_bf16( \
          aR0[m_], B0A[n_], acc[(MH)*4+m_][(NH)*2+n_], 0, 0, 0); \
      acc[(MH)*4+m_][(NH)*2+n_] = __builtin_amdgcn_mfma_f32_16x16x32_bf16( \
          aR1[m_], B1A[n_], acc[(MH)*4+m_][(NH)*2+n_], 0, 0, 0); \
    } \
} while (0)

// Per K-tile. vmcnt FIFO (steady state), issue order:
//   enter: B(T+1) 4 in flight
//   P1: ARL0+ARL1(T+1) +8        -> 12
//   P3: STAGEB B0(T+2) +2        -> 14; W3=vmcnt(2): drains B(T+1)+ARL,
//       keeps B0(T+2); then AWR both halves -> BUF^1
//   P4: STAGEB B1(T+2) +2; NO wait -> exit with B(T+2) 4 in flight
#define TILE_F(BUF, T, DOA, DOB, W3) do { \
  ALD(BUF, 0); \
  _Pragma("unroll") for (int n_ = 0; n_ < 2; ++n_) { \
    bL0[n_] = LDB(BUF, 0, n_, 0); bL1[n_] = LDB(BUF, 0, n_, 1); } \
  if (DOA) { ARL0((T) + 1); ARL1((T) + 1); } \
  __builtin_amdgcn_s_barrier(); \
  LGKM0_FENCE; \
  __builtin_amdgcn_s_setprio(1); QUAD(0, 0, bL0, bL1); __builtin_amdgcn_s_setprio(0); \
  __builtin_amdgcn_s_barrier(); \
  _Pragma("unroll") for (int n_ = 0; n_ < 2; ++n_) { \
    bH0[n_] = LDB(BUF, 1, n_, 0); bH1[n_] = LDB(BUF, 1, n_, 1); } \
  __builtin_amdgcn_s_barrier(); \
  LGKM0_FENCE; \
  __builtin_amdgcn_s_setprio(1); QUAD(0, 1, bH0, bH1); __builtin_amdgcn_s_setprio(0); \
  __builtin_amdgcn_s_barrier(); \
  ALD(BUF, 1); \
  if (DOB) STAGEB(BUF, 0, (T) + 2); \
  W3; \
  if (DOA) { AWR((BUF) ^ 1, 0, a0f); AWR((BUF) ^ 1, 1, a1f); } \
  __builtin_amdgcn_s_barrier(); \
  LGKM0_FENCE; \
  __builtin_amdgcn_s_setprio(1); QUAD(1, 0, bL0, bL1); __builtin_amdgcn_s_setprio(0); \
  __builtin_amdgcn_s_barrier(); \
  if (DOB) STAGEB(BUF, 1, (T) + 2); \
  __builtin_amdgcn_s_barrier(); \
  __builtin_amdgcn_s_setprio(1); QUAD(1, 1, bH0, bH1); __builtin_amdgcn_s_setprio(0); \
  __builtin_amdgcn_s_barrier(); \
} while (0)

__global__ __launch_bounds__(512, 2) void k_gemm10(
    const float* __restrict__ W,            // [8192][8192] fp32 raw weight
    const int* __restrict__ s1v, const int* __restrict__ s2v,
    const unsigned short* __restrict__ Bw,  // [2048][8192] bf16
    const float* __restrict__ bias,         // [2048]
    float* __restrict__ C) {                // [8192][2048] fp32
  __shared__ unsigned short sm[2 * 32768];  // 128 KiB
  unsigned short* smu = sm;
  const char* smb = (const char*)sm;
  char* smw = (char*)sm;

  const int tid  = threadIdx.x;
  const int lane = tid & 63;
  const int wave = tid >> 6;
  const int wr = wave >> 2;              // 0..1 -> 128-row half of A
  const int wc = wave & 3;               // 0..3 -> 64-col slice of B
  // XCD-grouped mapping (round-6, verified: FETCH 1.07GB -> 276MB): all 8
  // blocks sharing an A-panel (same bm) sit on XCD bid&7.
  const int g  = blockIdx.x & 7;
  const int bm = g * 4 + ((blockIdx.x >> 3) & 3);  // 0..31
  const int bn = blockIdx.x >> 5;                  // 0..7
  const int l15 = lane & 15;

  const unsigned short* gB = Bw + (size_t)bn * 256 * K_TOT;

  // B staging source (pre-swizzled slot; key = row&7, round-invariant)
  const int row0 = tid >> 3;
  const int row1 = 64 + row0;
  const int sl0  = (((tid & 7) ^ (row0 & 7)) << 3);

  // A reg-staging: thread owns row arow (per half), 16 floats at (tid&3)*16
  const int arow = tid >> 2;
  const int c16  = (tid & 3) << 4;
  const int rA0 = bm * 256 + arow;
  const int rA1 = rA0 + 128;
  const float* pA0 = W + (size_t)rA0 * K_TOT + c16;
  const float* pA1 = W + (size_t)rA1 * K_TOT + c16;
  const int PA0 = perm_pack(s1v[rA0] != 0, s2v[rA0] != 0);
  const int PA1 = perm_pack(s1v[rA1] != 0, s2v[rA1] != 0);
  const int wb0 = ((((tid & 3) * 2)    ) ^ (arow & 7)) << 4;
  const int wb1 = ((((tid & 3) * 2) | 1) ^ (arow & 7)) << 4;

  // ds_read col bases: byte col = (kk*64 | k16*16) ^ ((lane&7)<<4)
  int colsw[2];
  colsw[0] = (((lane >> 4) << 4)) ^ ((lane & 7) << 4);
  colsw[1] = (64 | ((lane >> 4) << 4)) ^ ((lane & 7) << 4);
  const int aBase = (wr * 128 + l15) * 128;
  const int bBase = (wc * 64 + l15) * 128;

  f32x4 acc[8][4];
#pragma unroll
  for (int i = 0; i < 8; ++i)
#pragma unroll
    for (int j = 0; j < 4; ++j) {
      acc[i][j][0] = 0.f; acc[i][j][1] = 0.f; acc[i][j][2] = 0.f; acc[i][j][3] = 0.f;
    }
  bf16x8 aR0[4], aR1[4], bL0[2], bL1[2], bH0[2], bH1[2];
  f32x4 a0f[4], a1f[4];

  // prologue: B(0)->buf0, B(1)->buf1; A(0) via regs -> buf0
  STAGEB(0, 0, 0); STAGEB(0, 1, 0);
  STAGEB(1, 0, 1); STAGEB(1, 1, 1);
  ARL0(0); ARL1(0);
  VM0;
  AWR(0, 0, a0f); AWR(0, 1, a1f);
  LGKM0_FENCE;
  __builtin_amdgcn_s_barrier();

  for (int t = 0; t < 124; t += 2) {
    TILE_F(0, t,     true, true, VM2);
    TILE_F(1, t + 1, true, true, VM2);
  }
  TILE_F(0, 124, true,  true,  VM2);
  TILE_F(1, 125, true,  true,  VM2);
  TILE_F(0, 126, true,  false, VM0);  // no B-stage: must fully drain ARL(127)
  TILE_F(1, 127, false, false, NOW);

  // epilogue: C/D layout col = lane&15, row = (lane>>4)*4 + j
  const int crow0 = bm * 256 + wr * 128 + ((lane >> 4) << 2);
  const int ccol0 = bn * 256 + wc * 64 + l15;
  float bv[4];
#pragma unroll
  for (int n = 0; n < 4; ++n) bv[n] = bias[ccol0 + n * 16];
#pragma unroll
  for (int mi = 0; mi < 8; ++mi)
#pragma unroll
    for (int ni = 0; ni < 4; ++ni) {
      const int r = crow0 + mi * 16;
      const int c = ccol0 + ni * 16;
#pragma unroll
      for (int j = 0; j < 4; ++j)
        C[(size_t)(r + j) * N_OUT + c] = acc[mi][ni][j] + bv[ni];
    }
}

// -------- fallback: fp32 tiled GEMM with inline permutation (ws too small) ----
__global__ __launch_bounds__(256) void k_gemm_fallback(
    const float* __restrict__ W, const float* __restrict__ FW,
    const float* __restrict__ bias, const int* __restrict__ s1v,
    const int* __restrict__ s2v, float* __restrict__ C) {
  __shared__ float As[64][33];
  __shared__ float Bs[64][33];
  const int tid = threadIdx.x;
  const int tx = tid & 15, ty = tid >> 4;
  const int bm = blockIdx.x & 127;
  const int bn = blockIdx.x >> 7;
  float acc[4][4] = {{0.f}};
  for (int k0 = 0; k0 < K_TOT; k0 += 32) {
#pragma unroll
    for (int i = 0; i < 8; ++i) {
      int idx = i * 256 + tid;
      int rr = idx >> 5, cc = idx & 31;
      int grow = bm * 64 + rr;
      int gk = k0 + cc;
      int blkr = gk >> 11, within = gk & 2047;
      int s1 = s1v[grow] != 0, s2 = s2v[grow] != 0;
      int pr = perm_src(blkr, s1, s2);
      As[rr][cc] = W[(size_t)grow * K_TOT + (size_t)pr * 2048 + within];
      Bs[rr][cc] = FW[(size_t)(bn * 64 + rr) * K_TOT + gk];
    }
    __syncthreads();
#pragma unroll 8
    for (int kk = 0; kk < 32; ++kk) {
      float a[4], b[4];
#pragma unroll
      for (int i = 0; i < 4; ++i) a[i] = As[ty * 4 + i][kk];
#pragma unroll
      for (int j = 0; j < 4; ++j) b[j] = Bs[tx * 4 + j][kk];
#pragma unroll
      for (int i = 0; i < 4; ++i)
#pragma unroll
        for (int j = 0; j < 4; ++j) acc[i][j] += a[i] * b[j];
    }
    __syncthreads();
  }
#pragma unroll
  for (int i = 0; i < 4; ++i)
#pragma unroll
    for (int j = 0; j < 4; ++j) {
      int r = bm * 64 + ty * 4 + i, c = bn * 64 + tx * 4 + j;
      C[(size_t)r * N_OUT + c] = acc[i][j] + bias[c];
    }
}

extern "C" void kernel_launch(void* const* d_in, const int* in_sizes, int n_in,
                              void* d_out, int out_size, void* d_ws, size_t ws_size,
                              hipStream_t stream) {
  const float* weight = (const float*)d_in[0];  // [8192][8192]
  const float* fc_w   = (const float*)d_in[1];  // [2048][8192]
  const float* fc_b   = (const float*)d_in[2];  // [2048]
  const int*   swap1  = (const int*)d_in[3];    // [8192]
  const int*   swap2  = (const int*)d_in[4];    // [8192]
  float* out = (float*)d_out;

  const size_t wbf_bytes = (size_t)N_OUT * K_TOT * 2;  // 32 MB
  if (ws_size >= wbf_bytes) {
    unsigned short* wbf = (unsigned short*)d_ws;
    k_prep_w<<<(N_OUT * K_TOT) / 2048, 256, 0, stream>>>(fc_w, wbf);
    k_gemm10<<<32 * 8, 512, 0, stream>>>(weight, swap1, swap2, wbf, fc_b, out);
  } else {
    k_gemm_fallback<<<128 * 32, 256, 0, stream>>>(weight, fc_w, fc_b, swap1,
                                                  swap2, out);
  }
}

// Round 10
// 290.720 us; speedup vs baseline: 1.2715x; 1.2715x over previous
//
#include <hip/hip_runtime.h>
#include <hip/hip_bf16.h>
#include <stdint.h>

// out[b, n] = sum_k weight[b, perm(k)] * fc_w[n, k] + fc_b[n]
// ROUND-10: revert to the measured-best split architecture (r2: 228us GEMM),
// with (1) prep merged into one launch (r3-measured ~55us) and (2) the
// r6-verified XCD-grouped block map on the GEMM (A-panels L2-pinned per XCD).
// GEMM body is r2's k_gemm8 verbatim otherwise: 256^2 tile, 8-phase, slot-XOR
// swizzle, counted vmcnt(4), setprio.

using f32x4   = __attribute__((ext_vector_type(4))) float;
using bf16x8  = __attribute__((ext_vector_type(8))) __bf16;
using ushort8 = __attribute__((ext_vector_type(8))) unsigned short;

#define B_ROWS 8192
#define K_TOT  8192
#define N_OUT  2048
#define BK     64
#define NT     (K_TOT / BK)  // 128 K-tiles

__device__ __forceinline__ unsigned short f2bf(float f) {
  union { float f; unsigned int u; } v;
  v.f = f;
  unsigned int r = v.u + 0x7FFFu + ((v.u >> 16) & 1u);  // RNE
  return (unsigned short)(r >> 16);
}

__device__ __forceinline__ int perm_src(int r, int s1, int s2) {
  int mid = s1 ? 1 : 2;
  return (r == 0) ? 0
       : (r == 1) ? (s1 ? 2 : 1)
       : (r == 2) ? (s2 ? 3 : mid)
                  : (s2 ? mid : 3);
}

// -------- prep (merged): permute+convert weight; convert fc_w --------
__global__ __launch_bounds__(256) void k_prep(
    const float* __restrict__ w, const int* __restrict__ s1v,
    const int* __restrict__ s2v, const float* __restrict__ fw,
    unsigned short* __restrict__ xbf, unsigned short* __restrict__ wbf) {
  const int blk = blockIdx.x;
  const float* src;
  unsigned short* dst;
  if (blk < B_ROWS * 4) {
    const int b = blk >> 2, r = blk & 3;
    const int s1 = s1v[b] != 0, s2 = s2v[b] != 0;
    const int pr = perm_src(r, s1, s2);
    src = w + (size_t)b * K_TOT + (size_t)pr * 2048 + threadIdx.x * 8;
    dst = xbf + (size_t)b * K_TOT + (size_t)r * 2048 + threadIdx.x * 8;
  } else {
    const size_t base = ((size_t)(blk - B_ROWS * 4) * 256 + threadIdx.x) * 8;
    src = fw + base;
    dst = wbf + base;
  }
  f32x4 v0 = *(const f32x4*)src;
  f32x4 v1 = *(const f32x4*)(src + 4);
  ushort8 o;
#pragma unroll
  for (int j = 0; j < 4; ++j) o[j] = f2bf(v0[j]);
#pragma unroll
  for (int j = 0; j < 4; ++j) o[4 + j] = f2bf(v1[j]);
  *(ushort8*)dst = o;
}

// -------- GEMM: r2's k_gemm8 (256x256-tile 8-phase bf16) --------
__device__ __forceinline__ void gload16(const unsigned short* g,
                                        const unsigned short* l) {
  __builtin_amdgcn_global_load_lds(
      (__attribute__((address_space(1))) void*)(uintptr_t)(const void*)g,
      (__attribute__((address_space(3))) void*)(unsigned int)(uintptr_t)(const void*)l,
      16, 0, 0);
}

// LDS: sm[buf(2)][ A:16384 | B:16384 ] ushorts = 128 KiB total.
// Tile layout per operand: [256 rows][64 cols] bf16, 128 B/row = 8 x 16B slots.
// Swizzle: 16B slot s of row r holds global slot (s ^ (r&7)) — involution,
// applied on the global SOURCE address at staging and on ds_read addresses.

#define VMW4 asm volatile("s_waitcnt vmcnt(4)" ::: "memory")
#define VMW0 asm volatile("s_waitcnt vmcnt(0)" ::: "memory")
#define VMWN ((void)0)
#define LGKM0_FENCE do { \
    asm volatile("s_waitcnt lgkmcnt(0)" ::: "memory"); \
    __builtin_amdgcn_sched_barrier(0); } while (0)

#define LDA(BU, MH, M, KKI) \
  (*(const bf16x8*)(smb + (BU)*65536 + aBase + ((MH)*64 + (M)*16)*128 + colsw[KKI]))
#define LDB(BU, NH, N, KKI) \
  (*(const bf16x8*)(smb + (BU)*65536 + 32768 + bBase + ((NH)*32 + (N)*16)*128 + colsw[KKI]))

// one half-tile (128 rows x 64 cols) = 2 global_load_lds x 512 threads
#define STAGE(BU, OPL, GOP, H, T) do { \
  gload16((GOP) + (size_t)((H)*128 + row0) * K_TOT + (size_t)(T)*BK + sl0, \
          smu + (BU)*32768 + (OPL) + (H)*8192 + tid*8); \
  gload16((GOP) + (size_t)((H)*128 + row1) * K_TOT + (size_t)(T)*BK + sl1, \
          smu + (BU)*32768 + (OPL) + (H)*8192 + 4096 + tid*8); \
} while (0)

#define QUAD(MH, NH, B0A, B1A) do { \
  _Pragma("unroll") for (int m_ = 0; m_ < 4; ++m_) \
    _Pragma("unroll") for (int n_ = 0; n_ < 2; ++n_) { \
      acc[(MH)*4+m_][(NH)*2+n_] = __builtin_amdgcn_mfma_f32_16x16x32_bf16( \
          aR0[m_], B0A[n_], acc[(MH)*4+m_][(NH)*2+n_], 0, 0, 0); \
      acc[(MH)*4+m_][(NH)*2+n_] = __builtin_amdgcn_mfma_f32_16x16x32_bf16( \
          aR1[m_], B1A[n_], acc[(MH)*4+m_][(NH)*2+n_], 0, 0, 0); \
    } \
} while (0)

// Per K-tile: 4 phases (r2-verified schedule).
//  P1: ds A-lo(8)+B-lo(4);  stage A0(t+1) -> other buf
//  P2: ds B-hi(4);          stage A1(t+1) -> other buf
//  P3: ds A-hi(8);          stage B0(t+2) -> CURRENT buf (B reads done @P2)
//  P4: no ds;               stage B1(t+2) -> CURRENT buf; counted vmcnt
#define TILE(BU, T, DOA, DOB, WAIT) do { \
  _Pragma("unroll") for (int m_ = 0; m_ < 4; ++m_) { \
    aR0[m_] = LDA(BU, 0, m_, 0); aR1[m_] = LDA(BU, 0, m_, 1); } \
  _Pragma("unroll") for (int n_ = 0; n_ < 2; ++n_) { \
    bL0[n_] = LDB(BU, 0, n_, 0); bL1[n_] = LDB(BU, 0, n_, 1); } \
  if (DOA) STAGE((BU) ^ 1, 0, gA, 0, (T) + 1); \
  __builtin_amdgcn_s_barrier(); \
  LGKM0_FENCE; \
  __builtin_amdgcn_s_setprio(1); QUAD(0, 0, bL0, bL1); __builtin_amdgcn_s_setprio(0); \
  __builtin_amdgcn_s_barrier(); \
  _Pragma("unroll") for (int n_ = 0; n_ < 2; ++n_) { \
    bH0[n_] = LDB(BU, 1, n_, 0); bH1[n_] = LDB(BU, 1, n_, 1); } \
  if (DOA) STAGE((BU) ^ 1, 0, gA, 1, (T) + 1); \
  __builtin_amdgcn_s_barrier(); \
  LGKM0_FENCE; \
  __builtin_amdgcn_s_setprio(1); QUAD(0, 1, bH0, bH1); __builtin_amdgcn_s_setprio(0); \
  __builtin_amdgcn_s_barrier(); \
  _Pragma("unroll") for (int m_ = 0; m_ < 4; ++m_) { \
    aR0[m_] = LDA(BU, 1, m_, 0); aR1[m_] = LDA(BU, 1, m_, 1); } \
  if (DOB) STAGE(BU, 16384, gB, 0, (T) + 2); \
  __builtin_amdgcn_s_barrier(); \
  LGKM0_FENCE; \
  __builtin_amdgcn_s_setprio(1); QUAD(1, 0, bL0, bL1); __builtin_amdgcn_s_setprio(0); \
  __builtin_amdgcn_s_barrier(); \
  if (DOB) STAGE(BU, 16384, gB, 1, (T) + 2); \
  __builtin_amdgcn_s_barrier(); \
  __builtin_amdgcn_s_setprio(1); QUAD(1, 1, bH0, bH1); __builtin_amdgcn_s_setprio(0); \
  WAIT; \
  __builtin_amdgcn_s_barrier(); \
} while (0)

__global__ __launch_bounds__(512, 2) void k_gemm8(
    const unsigned short* __restrict__ A,   // [8192][8192] bf16 (permuted)
    const unsigned short* __restrict__ Bw,  // [2048][8192] bf16
    const float* __restrict__ bias,         // [2048]
    float* __restrict__ C) {                // [8192][2048] fp32
  __shared__ unsigned short sm[2 * 32768];  // 128 KiB
  unsigned short* smu = sm;
  const char* smb = (const char*)sm;

  const int tid  = threadIdx.x;
  const int lane = tid & 63;
  const int wave = tid >> 6;
  const int wr = wave >> 2;              // 0..1 -> 128-row half
  const int wc = wave & 3;               // 0..3 -> 64-col slice
  // ROUND-10 CHANGE (only): XCD-grouped map (r6-verified FETCH mechanics).
  // XCD g owns A-panels g*4..g*4+3; its 8 blocks (4 bm x ... ) read A via L2.
  const int g  = blockIdx.x & 7;
  const int bm = g * 4 + ((blockIdx.x >> 3) & 3);  // 0..31
  const int bn = blockIdx.x >> 5;                  // 0..7

  const unsigned short* gA = A  + (size_t)bm * 256 * K_TOT;
  const unsigned short* gB = Bw + (size_t)bn * 256 * K_TOT;

  // staging address precompute (chunk ci = round*512 + tid; 8 slots/row)
  const int row0 = tid >> 3;
  const int sl0  = (((tid & 7) ^ (row0 & 7)) << 3);  // element offset of 16B slot
  const int row1 = (512 + tid) >> 3;
  const int sl1  = ((((512 + tid) & 7) ^ (row1 & 7)) << 3);

  // ds_read address precompute: byte col = (kk*64 | hi16*16) ^ ((lane&7)<<4)
  const int l15 = lane & 15;
  int colsw[2];
  colsw[0] = (((lane >> 4) << 4)) ^ ((lane & 7) << 4);
  colsw[1] = (64 | ((lane >> 4) << 4)) ^ ((lane & 7) << 4);
  const int aBase = (wr * 128 + l15) * 128;
  const int bBase = (wc * 64 + l15) * 128;

  f32x4 acc[8][4];
#pragma unroll
  for (int i = 0; i < 8; ++i)
#pragma unroll
    for (int j = 0; j < 4; ++j) {
      acc[i][j][0] = 0.f; acc[i][j][1] = 0.f; acc[i][j][2] = 0.f; acc[i][j][3] = 0.f;
    }
  bf16x8 aR0[4], aR1[4], bL0[2], bL1[2], bH0[2], bH1[2];

  // prologue: tile0 fully + B-halves of tile1; wait tile0 landed (vmcnt(4))
  STAGE(0, 0,     gA, 0, 0);
  STAGE(0, 0,     gA, 1, 0);
  STAGE(0, 16384, gB, 0, 0);
  STAGE(0, 16384, gB, 1, 0);
  STAGE(1, 16384, gB, 0, 1);
  STAGE(1, 16384, gB, 1, 1);
  VMW4;
  __builtin_amdgcn_s_barrier();

  int t = 0;
  for (; t < NT - 4; t += 2) {   // t = 0,2,...,122
    TILE(0, t,     true, true, VMW4);
    TILE(1, t + 1, true, true, VMW4);
  }
  TILE(0, 124, true,  true,  VMW4);
  TILE(1, 125, true,  true,  VMW4);
  TILE(0, 126, true,  false, VMW0);   // stages A(127) only; full drain
  TILE(1, 127, false, false, VMWN);   // last tile: no staging, no wait

  // epilogue: C/D layout col = lane&15, row = (lane>>4)*4 + j
  const int crow0 = bm * 256 + wr * 128 + ((lane >> 4) << 2);
  const int ccol0 = bn * 256 + wc * 64 + l15;
  float bv[4];
#pragma unroll
  for (int n = 0; n < 4; ++n) bv[n] = bias[ccol0 + n * 16];
#pragma unroll
  for (int mi = 0; mi < 8; ++mi)
#pragma unroll
    for (int ni = 0; ni < 4; ++ni) {
      const int r = crow0 + mi * 16;
      const int c = ccol0 + ni * 16;
#pragma unroll
      for (int j = 0; j < 4; ++j)
        C[(size_t)(r + j) * N_OUT + c] = acc[mi][ni][j] + bv[ni];
    }
}

// -------- fallback: fp32 tiled GEMM with inline permutation (ws too small) ----
__global__ __launch_bounds__(256) void k_gemm_fallback(
    const float* __restrict__ W, const float* __restrict__ FW,
    const float* __restrict__ bias, const int* __restrict__ s1v,
    const int* __restrict__ s2v, float* __restrict__ C) {
  __shared__ float As[64][33];
  __shared__ float Bs[64][33];
  const int tid = threadIdx.x;
  const int tx = tid & 15, ty = tid >> 4;
  const int bm = blockIdx.x & 127;
  const int bn = blockIdx.x >> 7;
  float acc[4][4] = {{0.f}};
  for (int k0 = 0; k0 < K_TOT; k0 += 32) {
#pragma unroll
    for (int i = 0; i < 8; ++i) {
      int idx = i * 256 + tid;
      int rr = idx >> 5, cc = idx & 31;
      int grow = bm * 64 + rr;
      int gk = k0 + cc;
      int blkr = gk >> 11, within = gk & 2047;
      int s1 = s1v[grow] != 0, s2 = s2v[grow] != 0;
      int pr = perm_src(blkr, s1, s2);
      As[rr][cc] = W[(size_t)grow * K_TOT + (size_t)pr * 2048 + within];
      Bs[rr][cc] = FW[(size_t)(bn * 64 + rr) * K_TOT + gk];
    }
    __syncthreads();
#pragma unroll 8
    for (int kk = 0; kk < 32; ++kk) {
      float a[4], b[4];
#pragma unroll
      for (int i = 0; i < 4; ++i) a[i] = As[ty * 4 + i][kk];
#pragma unroll
      for (int j = 0; j < 4; ++j) b[j] = Bs[tx * 4 + j][kk];
#pragma unroll
      for (int i = 0; i < 4; ++i)
#pragma unroll
        for (int j = 0; j < 4; ++j) acc[i][j] += a[i] * b[j];
    }
    __syncthreads();
  }
#pragma unroll
  for (int i = 0; i < 4; ++i)
#pragma unroll
    for (int j = 0; j < 4; ++j) {
      int r = bm * 64 + ty * 4 + i, c = bn * 64 + tx * 4 + j;
      C[(size_t)r * N_OUT + c] = acc[i][j] + bias[c];
    }
}

extern "C" void kernel_launch(void* const* d_in, const int* in_sizes, int n_in,
                              void* d_out, int out_size, void* d_ws, size_t ws_size,
                              hipStream_t stream) {
  const float* weight = (const float*)d_in[0];  // [8192][8192]
  const float* fc_w   = (const float*)d_in[1];  // [2048][8192]
  const float* fc_b   = (const float*)d_in[2];  // [2048]
  const int*   swap1  = (const int*)d_in[3];    // [8192]
  const int*   swap2  = (const int*)d_in[4];    // [8192]
  float* out = (float*)d_out;

  const size_t xbf_bytes = (size_t)B_ROWS * K_TOT * 2;  // 128 MB
  const size_t wbf_bytes = (size_t)N_OUT * K_TOT * 2;   //  32 MB
  if (ws_size >= xbf_bytes + wbf_bytes) {
    unsigned short* xbf = (unsigned short*)d_ws;
    unsigned short* wbf = (unsigned short*)((char*)d_ws + xbf_bytes);
    k_prep<<<B_ROWS * 4 + (N_OUT * K_TOT) / 2048, 256, 0, stream>>>(
        weight, swap1, swap2, fc_w, xbf, wbf);
    k_gemm8<<<32 * 8, 512, 0, stream>>>(xbf, wbf, fc_b, out);
  } else {
    k_gemm_fallback<<<128 * 32, 256, 0, stream>>>(weight, fc_w, fc_b, swap1,
                                                  swap2, out);
  }
}

// Round 13
// 280.977 us; speedup vs baseline: 1.3156x; 1.0347x over previous
//
#include <hip/hip_runtime.h>
#include <hip/hip_bf16.h>
#include <stdint.h>

// out[b, n] = sum_k weight[b, perm(k)] * fc_w[n, k] + fc_b[n]
// ROUND-11: split architecture (r10: prep 58us + GEMM 233us), GEMM upgraded
// with a B-fragment prefetch pipeline at ZERO VGPR cost:
//  - bH(t) ds_reads issue INSIDE P1's MFMA cluster (drained at P2 lgkm0)
//  - bL(t+1) ds_reads issue INSIDE P4's MFMA cluster (cross-tile), enabled by
//    moving the tile-end vmcnt(4)+publish-barrier BEFORE P4's MFMA
//  - barriers 8 -> 4 per tile; A reads stay same-phase (they overlap the
//    barrier wait already)
// Hazard trace (1-barrier-per-phase):
//  WAR: B-lo(t) last read-issued t-1.P4 region, drained at each wave's t.P1
//       lgkm0; B0(t+2) staged at t.P3-serial, which is after ALL waves passed
//       t.P2 barrier (hence past their P1 lgkm0). 2-barrier separation. OK.
//       B-hi(t) reads drained at P2 lgkm0; B1(t+2) staged after P3 barrier. OK.
//       A(t+1) staged t.P1/P2 into nxt; nxt A last read t-1.P3 serial, drained
//       at t-1.P3 lgkm0, all waves past it at t-1.P4 barrier. OK.
//  RAW: A(t),B(t) staged <= t-1.P2; drained at t-1.P4 vmcnt(4)+barrier before
//       any t reads. bL(t+1) prefetch at t.P4 is after the same drain of
//       B0/B1(t+1)+A(t+1). OK.
// Barriers are asm volatile s_barrier (memory clobber) so prefetch reads
// cannot hoist above the publish barrier.
// ROUND-12/13: identical resubmits — rounds 11 and 12 died on infra
// (UnresponsiveContainer, same dead container), produced no measurement.

using f32x4   = __attribute__((ext_vector_type(4))) float;
using bf16x8  = __attribute__((ext_vector_type(8))) __bf16;
using ushort8 = __attribute__((ext_vector_type(8))) unsigned short;

#define B_ROWS 8192
#define K_TOT  8192
#define N_OUT  2048
#define BK     64
#define NT     (K_TOT / BK)  // 128 K-tiles

__device__ __forceinline__ unsigned short f2bf(float f) {
  union { float f; unsigned int u; } v;
  v.f = f;
  unsigned int r = v.u + 0x7FFFu + ((v.u >> 16) & 1u);  // RNE
  return (unsigned short)(r >> 16);
}

__device__ __forceinline__ int perm_src(int r, int s1, int s2) {
  int mid = s1 ? 1 : 2;
  return (r == 0) ? 0
       : (r == 1) ? (s1 ? 2 : 1)
       : (r == 2) ? (s2 ? 3 : mid)
                  : (s2 ? mid : 3);
}

// -------- prep (merged): permute+convert weight; convert fc_w --------
__global__ __launch_bounds__(256) void k_prep(
    const float* __restrict__ w, const int* __restrict__ s1v,
    const int* __restrict__ s2v, const float* __restrict__ fw,
    unsigned short* __restrict__ xbf, unsigned short* __restrict__ wbf) {
  const int blk = blockIdx.x;
  const float* src;
  unsigned short* dst;
  if (blk < B_ROWS * 4) {
    const int b = blk >> 2, r = blk & 3;
    const int s1 = s1v[b] != 0, s2 = s2v[b] != 0;
    const int pr = perm_src(r, s1, s2);
    src = w + (size_t)b * K_TOT + (size_t)pr * 2048 + threadIdx.x * 8;
    dst = xbf + (size_t)b * K_TOT + (size_t)r * 2048 + threadIdx.x * 8;
  } else {
    const size_t base = ((size_t)(blk - B_ROWS * 4) * 256 + threadIdx.x) * 8;
    src = fw + base;
    dst = wbf + base;
  }
  f32x4 v0 = *(const f32x4*)src;
  f32x4 v1 = *(const f32x4*)(src + 4);
  ushort8 o;
#pragma unroll
  for (int j = 0; j < 4; ++j) o[j] = f2bf(v0[j]);
#pragma unroll
  for (int j = 0; j < 4; ++j) o[4 + j] = f2bf(v1[j]);
  *(ushort8*)dst = o;
}

// -------- GEMM --------
__device__ __forceinline__ void gload16(const unsigned short* g,
                                        const unsigned short* l) {
  __builtin_amdgcn_global_load_lds(
      (__attribute__((address_space(1))) void*)(uintptr_t)(const void*)g,
      (__attribute__((address_space(3))) void*)(unsigned int)(uintptr_t)(const void*)l,
      16, 0, 0);
}

#define VMW4 asm volatile("s_waitcnt vmcnt(4)" ::: "memory")
#define VMW0 asm volatile("s_waitcnt vmcnt(0)" ::: "memory")
#define VMWN ((void)0)
#define SBAR asm volatile("s_barrier" ::: "memory")
#define LGKM0_FENCE do { \
    asm volatile("s_waitcnt lgkmcnt(0)" ::: "memory"); \
    __builtin_amdgcn_sched_barrier(0); } while (0)

#define LDA(BU, MH, M, KKI) \
  (*(const bf16x8*)(smb + (BU)*65536 + aBase + ((MH)*64 + (M)*16)*128 + colsw[KKI]))
#define LDB(BU, NH, N, KKI) \
  (*(const bf16x8*)(smb + (BU)*65536 + 32768 + bBase + ((NH)*32 + (N)*16)*128 + colsw[KKI]))

// one half-tile (128 rows x 64 cols) = 2 global_load_lds x 512 threads
#define STAGE(BU, OPL, GOP, H, T) do { \
  gload16((GOP) + (size_t)((H)*128 + row0) * K_TOT + (size_t)(T)*BK + sl0, \
          smu + (BU)*32768 + (OPL) + (H)*8192 + tid*8); \
  gload16((GOP) + (size_t)((H)*128 + row1) * K_TOT + (size_t)(T)*BK + sl1, \
          smu + (BU)*32768 + (OPL) + (H)*8192 + 4096 + tid*8); \
} while (0)

#define QUAD(MH, NH, B0A, B1A) do { \
  _Pragma("unroll") for (int m_ = 0; m_ < 4; ++m_) \
    _Pragma("unroll") for (int n_ = 0; n_ < 2; ++n_) { \
      acc[(MH)*4+m_][(NH)*2+n_] = __builtin_amdgcn_mfma_f32_16x16x32_bf16( \
          aR0[m_], B0A[n_], acc[(MH)*4+m_][(NH)*2+n_], 0, 0, 0); \
      acc[(MH)*4+m_][(NH)*2+n_] = __builtin_amdgcn_mfma_f32_16x16x32_bf16( \
          aR1[m_], B1A[n_], acc[(MH)*4+m_][(NH)*2+n_], 0, 0, 0); \
    } \
} while (0)

// Per K-tile, 4 barriers. Phase layout:
//  P1: serial{read aLo(T); stage A0(T+1)->nxt}; bar; lgkm0;
//      MFMA aLo x bL  ||  prefetch bH(T)
//  P2: serial{stage A1(T+1)}; bar; lgkm0; MFMA aLo x bH
//  P3: serial{read aHi(T); stage B0(T+2)->cur}; bar; lgkm0; MFMA aHi x bL
//  P4: serial{stage B1(T+2)}; WV(vmcnt(4)); bar(publish);
//      MFMA aHi x bH  ||  prefetch bL(T+1) from nxt
#define TILE_N(BU, T, DOA, DOB, WV, DOPF) do { \
  _Pragma("unroll") for (int m_ = 0; m_ < 4; ++m_) { \
    aR0[m_] = LDA(BU, 0, m_, 0); aR1[m_] = LDA(BU, 0, m_, 1); } \
  if (DOA) STAGE((BU) ^ 1, 0, gA, 0, (T) + 1); \
  SBAR; \
  LGKM0_FENCE; \
  __builtin_amdgcn_s_setprio(1); \
  _Pragma("unroll") for (int n_ = 0; n_ < 2; ++n_) { \
    bH0[n_] = LDB(BU, 1, n_, 0); bH1[n_] = LDB(BU, 1, n_, 1); } \
  QUAD(0, 0, bL0, bL1); \
  __builtin_amdgcn_s_setprio(0); \
  if (DOA) STAGE((BU) ^ 1, 0, gA, 1, (T) + 1); \
  SBAR; \
  LGKM0_FENCE; \
  __builtin_amdgcn_s_setprio(1); \
  QUAD(0, 1, bH0, bH1); \
  __builtin_amdgcn_s_setprio(0); \
  _Pragma("unroll") for (int m_ = 0; m_ < 4; ++m_) { \
    aR0[m_] = LDA(BU, 1, m_, 0); aR1[m_] = LDA(BU, 1, m_, 1); } \
  if (DOB) STAGE(BU, 16384, gB, 0, (T) + 2); \
  SBAR; \
  LGKM0_FENCE; \
  __builtin_amdgcn_s_setprio(1); \
  QUAD(1, 0, bL0, bL1); \
  __builtin_amdgcn_s_setprio(0); \
  if (DOB) STAGE(BU, 16384, gB, 1, (T) + 2); \
  WV; \
  SBAR; \
  __builtin_amdgcn_s_setprio(1); \
  if (DOPF) { \
    _Pragma("unroll") for (int n_ = 0; n_ < 2; ++n_) { \
      bL0[n_] = LDB((BU) ^ 1, 0, n_, 0); bL1[n_] = LDB((BU) ^ 1, 0, n_, 1); } } \
  QUAD(1, 1, bH0, bH1); \
  __builtin_amdgcn_s_setprio(0); \
} while (0)

__global__ __launch_bounds__(512, 2) void k_gemm11(
    const unsigned short* __restrict__ A,   // [8192][8192] bf16 (permuted)
    const unsigned short* __restrict__ Bw,  // [2048][8192] bf16
    const float* __restrict__ bias,         // [2048]
    float* __restrict__ C) {                // [8192][2048] fp32
  __shared__ unsigned short sm[2 * 32768];  // 128 KiB
  unsigned short* smu = sm;
  const char* smb = (const char*)sm;

  const int tid  = threadIdx.x;
  const int lane = tid & 63;
  const int wave = tid >> 6;
  const int wr = wave >> 2;              // 0..1 -> 128-row half
  const int wc = wave & 3;               // 0..3 -> 64-col slice
  // XCD-grouped map (r10-verified: FETCH 540->197 MB)
  const int g  = blockIdx.x & 7;
  const int bm = g * 4 + ((blockIdx.x >> 3) & 3);  // 0..31
  const int bn = blockIdx.x >> 5;                  // 0..7

  const unsigned short* gA = A  + (size_t)bm * 256 * K_TOT;
  const unsigned short* gB = Bw + (size_t)bn * 256 * K_TOT;

  // staging address precompute (chunk ci = round*512 + tid; 8 slots/row)
  const int row0 = tid >> 3;
  const int sl0  = (((tid & 7) ^ (row0 & 7)) << 3);  // element offset of 16B slot
  const int row1 = (512 + tid) >> 3;
  const int sl1  = ((((512 + tid) & 7) ^ (row1 & 7)) << 3);

  // ds_read address precompute: byte col = (kk*64 | hi16*16) ^ ((lane&7)<<4)
  const int l15 = lane & 15;
  int colsw[2];
  colsw[0] = (((lane >> 4) << 4)) ^ ((lane & 7) << 4);
  colsw[1] = (64 | ((lane >> 4) << 4)) ^ ((lane & 7) << 4);
  const int aBase = (wr * 128 + l15) * 128;
  const int bBase = (wc * 64 + l15) * 128;

  f32x4 acc[8][4];
#pragma unroll
  for (int i = 0; i < 8; ++i)
#pragma unroll
    for (int j = 0; j < 4; ++j) {
      acc[i][j][0] = 0.f; acc[i][j][1] = 0.f; acc[i][j][2] = 0.f; acc[i][j][3] = 0.f;
    }
  bf16x8 aR0[4], aR1[4], bL0[2], bL1[2], bH0[2], bH1[2];

  // prologue: A(0),B(0)->buf0; B(1)->buf1; drain; publish; pre-read bL(0)
  STAGE(0, 0,     gA, 0, 0);
  STAGE(0, 0,     gA, 1, 0);
  STAGE(0, 16384, gB, 0, 0);
  STAGE(0, 16384, gB, 1, 0);
  STAGE(1, 16384, gB, 0, 1);
  STAGE(1, 16384, gB, 1, 1);
  VMW0;
  SBAR;
#pragma unroll
  for (int n_ = 0; n_ < 2; ++n_) {
    bL0[n_] = LDB(0, 0, n_, 0); bL1[n_] = LDB(0, 0, n_, 1);
  }

  for (int t = 0; t < 124; t += 2) {   // tiles 0..123
    TILE_N(0, t,     true, true, VMW4, true);
    TILE_N(1, t + 1, true, true, VMW4, true);
  }
  TILE_N(0, 124, true,  true,  VMW4, true);
  TILE_N(1, 125, true,  true,  VMW4, true);
  TILE_N(0, 126, true,  false, VMW0, true);   // drain all; prefetch bL(127)
  TILE_N(1, 127, false, false, VMWN, false);  // last: nothing staged

  // epilogue: C/D layout col = lane&15, row = (lane>>4)*4 + j
  const int crow0 = bm * 256 + wr * 128 + ((lane >> 4) << 2);
  const int ccol0 = bn * 256 + wc * 64 + l15;
  float bv[4];
#pragma unroll
  for (int n = 0; n < 4; ++n) bv[n] = bias[ccol0 + n * 16];
#pragma unroll
  for (int mi = 0; mi < 8; ++mi)
#pragma unroll
    for (int ni = 0; ni < 4; ++ni) {
      const int r = crow0 + mi * 16;
      const int c = ccol0 + ni * 16;
#pragma unroll
      for (int j = 0; j < 4; ++j)
        C[(size_t)(r + j) * N_OUT + c] = acc[mi][ni][j] + bv[ni];
    }
}

// -------- fallback: fp32 tiled GEMM with inline permutation (ws too small) ----
__global__ __launch_bounds__(256) void k_gemm_fallback(
    const float* __restrict__ W, const float* __restrict__ FW,
    const float* __restrict__ bias, const int* __restrict__ s1v,
    const int* __restrict__ s2v, float* __restrict__ C) {
  __shared__ float As[64][33];
  __shared__ float Bs[64][33];
  const int tid = threadIdx.x;
  const int tx = tid & 15, ty = tid >> 4;
  const int bm = blockIdx.x & 127;
  const int bn = blockIdx.x >> 7;
  float acc[4][4] = {{0.f}};
  for (int k0 = 0; k0 < K_TOT; k0 += 32) {
#pragma unroll
    for (int i = 0; i < 8; ++i) {
      int idx = i * 256 + tid;
      int rr = idx >> 5, cc = idx & 31;
      int grow = bm * 64 + rr;
      int gk = k0 + cc;
      int blkr = gk >> 11, within = gk & 2047;
      int s1 = s1v[grow] != 0, s2 = s2v[grow] != 0;
      int pr = perm_src(blkr, s1, s2);
      As[rr][cc] = W[(size_t)grow * K_TOT + (size_t)pr * 2048 + within];
      Bs[rr][cc] = FW[(size_t)(bn * 64 + rr) * K_TOT + gk];
    }
    __syncthreads();
#pragma unroll 8
    for (int kk = 0; kk < 32; ++kk) {
      float a[4], b[4];
#pragma unroll
      for (int i = 0; i < 4; ++i) a[i] = As[ty * 4 + i][kk];
#pragma unroll
      for (int j = 0; j < 4; ++j) b[j] = Bs[tx * 4 + j][kk];
#pragma unroll
      for (int i = 0; i < 4; ++i)
#pragma unroll
        for (int j = 0; j < 4; ++j) acc[i][j] += a[i] * b[j];
    }
    __syncthreads();
  }
#pragma unroll
  for (int i = 0; i < 4; ++i)
#pragma unroll
    for (int j = 0; j < 4; ++j) {
      int r = bm * 64 + ty * 4 + i, c = bn * 64 + tx * 4 + j;
      C[(size_t)r * N_OUT + c] = acc[i][j] + bias[c];
    }
}

extern "C" void kernel_launch(void* const* d_in, const int* in_sizes, int n_in,
                              void* d_out, int out_size, void* d_ws, size_t ws_size,
                              hipStream_t stream) {
  const float* weight = (const float*)d_in[0];  // [8192][8192]
  const float* fc_w   = (const float*)d_in[1];  // [2048][8192]
  const float* fc_b   = (const float*)d_in[2];  // [2048]
  const int*   swap1  = (const int*)d_in[3];    // [8192]
  const int*   swap2  = (const int*)d_in[4];    // [8192]
  float* out = (float*)d_out;

  const size_t xbf_bytes = (size_t)B_ROWS * K_TOT * 2;  // 128 MB
  const size_t wbf_bytes = (size_t)N_OUT * K_TOT * 2;   //  32 MB
  if (ws_size >= xbf_bytes + wbf_bytes) {
    unsigned short* xbf = (unsigned short*)d_ws;
    unsigned short* wbf = (unsigned short*)((char*)d_ws + xbf_bytes);
    k_prep<<<B_ROWS * 4 + (N_OUT * K_TOT) / 2048, 256, 0, stream>>>(
        weight, swap1, swap2, fc_w, xbf, wbf);
    k_gemm11<<<32 * 8, 512, 0, stream>>>(xbf, wbf, fc_b, out);
  } else {
    k_gemm_fallback<<<128 * 32, 256, 0, stream>>>(weight, fc_w, fc_b, swap1,
                                                  swap2, out);
  }
}